// Round 8
// baseline (160.231 us; speedup 1.0000x reference)
//
#include <hip/hip_runtime.h>
#include <hip/hip_bf16.h>
#include <math.h>

#define DIM  64
#define KN   16
#define NREL 32

__device__ __forceinline__ float frcp(float x) { return __builtin_amdgcn_rcpf(x); }

__device__ __forceinline__ unsigned short f2bf(float f) {
    unsigned u = __float_as_uint(f);
    u = (u + 0x7fffu + ((u >> 16) & 1u)) >> 16;   // RNE
    return (unsigned short)u;
}
__device__ __forceinline__ float bf2f(unsigned short b) {
    return __uint_as_float((unsigned)b << 16);
}

// ============================================================================
// Kernel 1: WEb[e][d] = bf16( sum_j W[d][j] * entity_emb[e][j] )
// 8 rows per wave, wave-private LDS staging, zero barriers. (unchanged R7)
// ============================================================================
__global__ __launch_bounds__(256, 4) void we_kernel(
    const float* __restrict__ entity_emb,
    const float* __restrict__ W,
    unsigned short* __restrict__ WEb,
    int nRows)
{
    __shared__ float4 xs_s[4][8 * 16];   // 2 KB per wave
    const int tid  = threadIdx.x;
    const int wave = tid >> 6;
    const int lane = tid & 63;
    float4* xs = xs_s[wave];

    const int base = (blockIdx.x * 4 + wave) * 8;
    if (base >= nRows) return;

    float4 Wr[16];
    const float4* W4 = (const float4*)(W + lane * DIM);
    #pragma unroll
    for (int j = 0; j < 16; ++j) Wr[j] = W4[j];

    const float4* src = (const float4*)entity_emb;
    #pragma unroll
    for (int i = 0; i < 2; ++i) {
        const int idx = i * 64 + lane;
        const int row = base + (idx >> 4);
        const size_t g = (row < nRows) ? ((size_t)base * 16 + idx) : 0;
        xs[idx] = src[g];
    }
    asm volatile("s_waitcnt lgkmcnt(0)" ::: "memory");

    #pragma unroll
    for (int r = 0; r < 8; ++r) {
        const int row = base + r;
        if (row >= nRows) break;
        float h0 = 0.f, h1 = 0.f, h2 = 0.f, h3 = 0.f;
        #pragma unroll
        for (int jc = 0; jc < 16; jc += 4) {
            float4 a = xs[r * 16 + jc + 0];
            float4 b = xs[r * 16 + jc + 1];
            float4 c = xs[r * 16 + jc + 2];
            float4 d = xs[r * 16 + jc + 3];
            h0 += a.x*Wr[jc+0].x + a.y*Wr[jc+0].y + a.z*Wr[jc+0].z + a.w*Wr[jc+0].w;
            h1 += b.x*Wr[jc+1].x + b.y*Wr[jc+1].y + b.z*Wr[jc+1].z + b.w*Wr[jc+1].w;
            h2 += c.x*Wr[jc+2].x + c.y*Wr[jc+2].y + c.z*Wr[jc+2].z + c.w*Wr[jc+2].w;
            h3 += d.x*Wr[jc+3].x + d.y*Wr[jc+3].y + d.z*Wr[jc+3].z + d.w*Wr[jc+3].w;
        }
        WEb[(size_t)row * DIM + lane] = f2bf((h0 + h1) + (h2 + h3));
    }
}

// ============================================================================
// Kernel 2: main. TWO waves per pair (8 groups each) -> 8192 waves, 2048
// blocks = 8 blocks/CU = up to 32 waves/CU: double the resident waves for
// the latency-bound WE gathers. One barrier; half-0 wave runs the hop-0
// tail. Layer-0 matvecs remain folded into the gathers via linearity.
// ============================================================================
__global__ __launch_bounds__(256, 4) void kgcn_main(
    const int* __restrict__ pairs,
    const int* __restrict__ adjE,
    const int* __restrict__ adjR,
    const unsigned short* __restrict__ WEb,
    const float* __restrict__ relation_emb,
    const float* __restrict__ user_emb,
    const float* __restrict__ W,
    const float* __restrict__ bias,
    float* __restrict__ out,
    int nPairs)
{
    __shared__ float ev1_s[2][KN * DIM];  // per-pair layer-0 outputs
    __shared__ float xb_s[2][DIM];        // per-pair matvec broadcast buffer

    const int tid  = threadIdx.x;
    const int wave = tid >> 6;      // 0..3
    const int lane = tid & 63;
    const int q    = wave >> 1;     // pair slot in block (0..1)
    const int half = wave & 1;      // which 8 groups this wave owns
    int p = blockIdx.x * 2 + q;
    if (p >= nPairs) p = nPairs - 1;   // keep barrier uniform

    float* ev1 = ev1_s[q];
    float* xb  = xb_s[q];

    const int user = pairs[2 * p + 0];
    const int item = pairs[2 * p + 1];

    const float bval = bias[lane];
    const unsigned short* WE_l = WEb + lane;

    // item adjacency row (both halves need e1 for group ids)
    int rk0 = 0, e1 = 0;
    if (lane < KN) {
        rk0 = adjR[(size_t)item * KN + lane];
        e1  = adjE[(size_t)item * KN + lane];
    }

    // dot(u, rel_r) for all 32 relations: 2 lanes per relation
    float acc;
    {
        const int r = lane >> 1, hlf = lane & 1;
        const float4* rel4 = (const float4*)(relation_emb + r * DIM + hlf * 32);
        const float4* u4   = (const float4*)(user_emb + (size_t)user * DIM + hlf * 32);
        float a0 = 0.f, a1 = 0.f;
        #pragma unroll
        for (int j = 0; j < 8; j += 2) {
            float4 a = rel4[j],     b = u4[j];
            float4 c = rel4[j + 1], d = u4[j + 1];
            a0 += a.x*b.x + a.y*b.y + a.z*b.z + a.w*b.w;
            a1 += c.x*d.x + c.y*d.y + c.z*d.z + c.w*d.w;
        }
        acc = a0 + a1;
        acc += __shfl_xor(acc, 1);
    }

    // softmax within 16-lane subgroups (4 independent groups per call)
    auto softmax16 = [&](float s) -> float {
        float mx = s;
        mx = fmaxf(mx, __shfl_xor(mx, 1));
        mx = fmaxf(mx, __shfl_xor(mx, 2));
        mx = fmaxf(mx, __shfl_xor(mx, 4));
        mx = fmaxf(mx, __shfl_xor(mx, 8));
        float e = __expf(s - mx);
        float ss = e;
        ss += __shfl_xor(ss, 1);
        ss += __shfl_xor(ss, 2);
        ss += __shfl_xor(ss, 4);
        ss += __shfl_xor(ss, 8);
        return e * frcp(ss);
    };

    // this wave's 8 groups, adjacency packed 4 rows per register slot:
    // slot c, subgroup m4 holds group half*8 + 4c + m4; lane m4*16+kk holds k=kk
    const int m4 = lane >> 4, kk = lane & 15;
    int ekA[2]; float wA[2];
    #pragma unroll
    for (int c = 0; c < 2; ++c) {
        const int g  = __shfl(e1, half * 8 + 4 * c + m4);
        const int rk = adjR[(size_t)(unsigned)g * KN + kk];
        ekA[c]       = adjE[(size_t)(unsigned)g * KN + kk];
        wA[c] = softmax16(__shfl(acc, rk << 1));
    }

    // layer 0, hop 1: 8 groups per wave, pure gathers from WEb (+bias, ReLU)
    #pragma unroll 2
    for (int m = 0; m < 8; ++m) {
        const int mg  = half * 8 + m;
        const int c   = m >> 2;
        const int sub = (m & 3) * 16;
        const int g   = __shfl(e1, mg);
        float ha = bf2f(WE_l[(size_t)(unsigned)g * DIM]) + bval;
        float hb = 0.f;
        #pragma unroll
        for (int k = 0; k < KN; k += 2) {
            const int   ea = __shfl(ekA[c], sub + k);
            const float fa = __shfl(wA[c],  sub + k);
            const int   eb = __shfl(ekA[c], sub + k + 1);
            const float fb = __shfl(wA[c],  sub + k + 1);
            ha += fa * bf2f(WE_l[(size_t)(unsigned)ea * DIM]);
            hb += fb * bf2f(WE_l[(size_t)(unsigned)eb * DIM]);
        }
        ev1[mg * DIM + lane] = fmaxf(ha + hb, 0.f);
    }

    __syncthreads();
    if (half != 0) return;   // one tail wave per pair

    // ---- hop 0, layer 0: gather from WEb with w0 ----
    const float w0 = softmax16(__shfl(acc, rk0 << 1));
    float ha = bf2f(WE_l[(size_t)item * DIM]) + bval;
    float hb = 0.f;
    #pragma unroll
    for (int k = 0; k < KN; k += 2) {
        const int   ea = __shfl(e1, k);
        const float fa = __shfl(w0, k);
        const int   eb = __shfl(e1, k + 1);
        const float fb = __shfl(w0, k + 1);
        ha += fa * bf2f(WE_l[(size_t)(unsigned)ea * DIM]);
        hb += fb * bf2f(WE_l[(size_t)(unsigned)eb * DIM]);
    }
    const float e0 = fmaxf(ha + hb, 0.f);

    // layer 1 aggregate: x1 = e0 + sum_m w0_m * ev1_m  (ev1 visible via barrier)
    float xa = e0, xc = 0.f;
    #pragma unroll
    for (int k = 0; k < KN; k += 2) {
        xa += __shfl(w0, k)     * ev1[k * DIM + lane];
        xc += __shfl(w0, k + 1) * ev1[(k + 1) * DIM + lane];
    }
    const float x1 = xa + xc;

    // the ONE real matvec: h1 = W x1 + b, via LDS broadcast
    asm volatile("s_waitcnt lgkmcnt(0)" ::: "memory");
    xb[lane] = x1;
    asm volatile("s_waitcnt lgkmcnt(0)" ::: "memory");
    float h0 = bval, h1 = 0.f, h2 = 0.f, h3 = 0.f;
    {
        const float4* Wl  = (const float4*)(W + lane * DIM);
        const float4* xv4 = (const float4*)xb;
        #pragma unroll
        for (int j = 0; j < 16; j += 4) {
            float4 w0v = Wl[j],   x0v = xv4[j];
            float4 w1v = Wl[j+1], x1v = xv4[j+1];
            float4 w2v = Wl[j+2], x2v = xv4[j+2];
            float4 w3v = Wl[j+3], x3v = xv4[j+3];
            h0 += w0v.x*x0v.x + w0v.y*x0v.y + w0v.z*x0v.z + w0v.w*x0v.w;
            h1 += w1v.x*x1v.x + w1v.y*x1v.y + w1v.z*x1v.z + w1v.w*x1v.w;
            h2 += w2v.x*x2v.x + w2v.y*x2v.y + w2v.z*x2v.z + w2v.w*x2v.w;
            h3 += w3v.x*x3v.x + w3v.y*x3v.y + w3v.z*x3v.z + w3v.w*x3v.w;
        }
    }
    const float itemf = tanhf((h0 + h1) + (h2 + h3));

    float d = user_emb[(size_t)user * DIM + lane] * itemf;
    d += __shfl_xor(d, 1);
    d += __shfl_xor(d, 2);
    d += __shfl_xor(d, 4);
    d += __shfl_xor(d, 8);
    d += __shfl_xor(d, 16);
    d += __shfl_xor(d, 32);
    if (lane == 0) out[p] = 1.f / (1.f + expf(-d));
}

// ============================================================================
// Fallback (verified R5 kernel) in case ws_size < WE table size.
// ============================================================================
__global__ __launch_bounds__(256, 4) void kgcn_fallback(
    const int* __restrict__ pairs, const int* __restrict__ adj_entity,
    const int* __restrict__ adj_relation, const float* __restrict__ entity_emb,
    const float* __restrict__ relation_emb, const float* __restrict__ user_emb,
    const float* __restrict__ W, const float* __restrict__ bias,
    float* __restrict__ out, int nPairs)
{
    __shared__ float ev1_s[2][KN * DIM];
    __shared__ float xb_s[4][DIM];
    const int tid = threadIdx.x, wave = tid >> 6, lane = tid & 63;
    const int q = wave >> 1, half = wave & 1;
    int p = blockIdx.x * 2 + q;
    if (p >= nPairs) p = nPairs - 1;
    float* ev1 = ev1_s[q]; float* xb = xb_s[wave];
    const int user = pairs[2 * p + 0], item = pairs[2 * p + 1];
    const float bval = bias[lane];
    const float* emb_l = entity_emb + lane;
    const float4* W4 = (const float4*)(W + lane * DIM);
    int rk0 = 0, e1 = 0;
    if (lane < KN) {
        rk0 = adj_relation[(size_t)item * KN + lane];
        e1  = adj_entity[(size_t)item * KN + lane];
    }
    float acc;
    {
        const int r = lane >> 1, hlf = lane & 1;
        const float4* rel4 = (const float4*)(relation_emb + r * DIM + hlf * 32);
        const float4* u4 = (const float4*)(user_emb + (size_t)user * DIM + hlf * 32);
        float a0 = 0.f, a1 = 0.f;
        #pragma unroll
        for (int j = 0; j < 8; j += 2) {
            float4 a = rel4[j], b = u4[j], c = rel4[j+1], d = u4[j+1];
            a0 += a.x*b.x + a.y*b.y + a.z*b.z + a.w*b.w;
            a1 += c.x*d.x + c.y*d.y + c.z*d.z + c.w*d.w;
        }
        acc = a0 + a1; acc += __shfl_xor(acc, 1);
    }
    auto softmax16 = [&](float s) -> float {
        float mx = s;
        mx = fmaxf(mx, __shfl_xor(mx, 1)); mx = fmaxf(mx, __shfl_xor(mx, 2));
        mx = fmaxf(mx, __shfl_xor(mx, 4)); mx = fmaxf(mx, __shfl_xor(mx, 8));
        float e = __expf(s - mx);
        float ss = e;
        ss += __shfl_xor(ss, 1); ss += __shfl_xor(ss, 2);
        ss += __shfl_xor(ss, 4); ss += __shfl_xor(ss, 8);
        return e * frcp(ss);
    };
    auto matvec = [&](float xv) -> float {
        asm volatile("s_waitcnt lgkmcnt(0)" ::: "memory");
        xb[lane] = xv;
        asm volatile("s_waitcnt lgkmcnt(0)" ::: "memory");
        float h0 = bval, h1 = 0.f, h2 = 0.f, h3 = 0.f;
        const float4* xv4 = (const float4*)xb;
        #pragma unroll
        for (int j = 0; j < 16; j += 4) {
            float4 w0 = W4[j], x0 = xv4[j], w1 = W4[j+1], x1 = xv4[j+1];
            float4 w2 = W4[j+2], x2 = xv4[j+2], w3 = W4[j+3], x3 = xv4[j+3];
            h0 += w0.x*x0.x + w0.y*x0.y + w0.z*x0.z + w0.w*x0.w;
            h1 += w1.x*x1.x + w1.y*x1.y + w1.z*x1.z + w1.w*x1.w;
            h2 += w2.x*x2.x + w2.y*x2.y + w2.z*x2.z + w2.w*x2.w;
            h3 += w3.x*x3.x + w3.y*x3.y + w3.z*x3.z + w3.w*x3.w;
        }
        return (h0 + h1) + (h2 + h3);
    };
    auto gather = [&](int self, int ek, float w) -> float {
        float xa = emb_l[(size_t)(unsigned)self * DIM], xc = 0.f;
        #pragma unroll
        for (int k = 0; k < KN; k += 2) {
            const int e0i = __shfl(ek, k); const float f0 = __shfl(w, k);
            const int e1i = __shfl(ek, k + 1); const float f1 = __shfl(w, k + 1);
            xa += f0 * emb_l[(size_t)(unsigned)e0i * DIM];
            xc += f1 * emb_l[(size_t)(unsigned)e1i * DIM];
        }
        return xa + xc;
    };
    int rk_n = 0, ek_n = 0;
    {
        const int g0 = __shfl(e1, half * 8);
        if (lane < KN) {
            rk_n = adj_relation[(size_t)(unsigned)g0 * KN + lane];
            ek_n = adj_entity[(size_t)(unsigned)g0 * KN + lane];
        }
    }
    #pragma unroll 1
    for (int mi = 0; mi < 8; ++mi) {
        const int m = half * 8 + mi;
        const int g = __shfl(e1, m);
        const int rk = rk_n, ek = ek_n;
        if (mi + 1 < 8) {
            const int gn = __shfl(e1, m + 1);
            if (lane < KN) {
                rk_n = adj_relation[(size_t)(unsigned)gn * KN + lane];
                ek_n = adj_entity[(size_t)(unsigned)gn * KN + lane];
            }
        }
        const float w = softmax16(__shfl(acc, rk << 1));
        const float x = gather(g, ek, w);
        ev1[m * DIM + lane] = fmaxf(matvec(x), 0.f);
    }
    __syncthreads();
    if (half != 0) return;
    const float w0 = softmax16(__shfl(acc, rk0 << 1));
    const float x0 = gather(item, e1, w0);
    const float e0 = fmaxf(matvec(x0), 0.f);
    float xa = e0, xc = 0.f;
    #pragma unroll
    for (int k = 0; k < KN; k += 2) {
        xa += __shfl(w0, k) * ev1[k * DIM + lane];
        xc += __shfl(w0, k + 1) * ev1[(k + 1) * DIM + lane];
    }
    const float itemf = tanhf(matvec(xa + xc));
    float d = user_emb[(size_t)user * DIM + lane] * itemf;
    d += __shfl_xor(d, 1); d += __shfl_xor(d, 2); d += __shfl_xor(d, 4);
    d += __shfl_xor(d, 8); d += __shfl_xor(d, 16); d += __shfl_xor(d, 32);
    if (lane == 0) out[p] = 1.f / (1.f + expf(-d));
}

extern "C" void kernel_launch(void* const* d_in, const int* in_sizes, int n_in,
                              void* d_out, int out_size, void* d_ws, size_t ws_size,
                              hipStream_t stream) {
    const int*   pairs        = (const int*)d_in[0];
    const int*   adj_entity   = (const int*)d_in[1];
    const int*   adj_relation = (const int*)d_in[2];
    const float* entity_emb   = (const float*)d_in[3];
    const float* relation_emb = (const float*)d_in[4];
    const float* user_emb     = (const float*)d_in[5];
    const float* W            = (const float*)d_in[6];
    const float* b            = (const float*)d_in[7];
    float* out = (float*)d_out;

    const int nPairs = in_sizes[0] / 2;          // pairs is (B, 2)
    const int nEnt   = in_sizes[3] / DIM;        // entity count
    const size_t weBytes = (size_t)in_sizes[3] * sizeof(unsigned short);

    if (ws_size >= weBytes) {
        unsigned short* WEb = (unsigned short*)d_ws;
        const int preBlocks = (nEnt + 8 * 4 - 1) / (8 * 4);   // 8 rows/wave
        we_kernel<<<preBlocks, 256, 0, stream>>>(entity_emb, W, WEb, nEnt);
        const int mainBlocks = (nPairs + 1) / 2;              // 2 pairs/block
        kgcn_main<<<mainBlocks, 256, 0, stream>>>(pairs, adj_entity, adj_relation,
                                                  WEb, relation_emb, user_emb,
                                                  W, b, out, nPairs);
    } else {
        const int nBlocks = (nPairs + 1) / 2;
        kgcn_fallback<<<nBlocks, 256, 0, stream>>>(pairs, adj_entity, adj_relation,
                                                   entity_emb, relation_emb, user_emb,
                                                   W, b, out, nPairs);
    }
}

// Round 9
// 147.586 us; speedup vs baseline: 1.0857x; 1.0857x over previous
//
#include <hip/hip_runtime.h>
#include <hip/hip_bf16.h>
#include <math.h>

#define DIM  64
#define KN   16
#define NREL 32

__device__ __forceinline__ float frcp(float x) { return __builtin_amdgcn_rcpf(x); }

__device__ __forceinline__ unsigned short f2bf(float f) {
    unsigned u = __float_as_uint(f);
    u = (u + 0x7fffu + ((u >> 16) & 1u)) >> 16;   // RNE
    return (unsigned short)u;
}
// bf16 pair packed in a dword: low ushort = even dim, high ushort = odd dim
__device__ __forceinline__ float bflo(unsigned v) { return __uint_as_float(v << 16); }
__device__ __forceinline__ float bfhi(unsigned v) { return __uint_as_float(v & 0xffff0000u); }

// ============================================================================
// Kernel 1: WEb[e][d] = bf16( sum_j W[d][j] * entity_emb[e][j] )  (unchanged)
// ============================================================================
__global__ __launch_bounds__(256, 4) void we_kernel(
    const float* __restrict__ entity_emb,
    const float* __restrict__ W,
    unsigned short* __restrict__ WEb,
    int nRows)
{
    __shared__ float4 xs_s[4][8 * 16];
    const int tid  = threadIdx.x;
    const int wave = tid >> 6;
    const int lane = tid & 63;
    float4* xs = xs_s[wave];

    const int base = (blockIdx.x * 4 + wave) * 8;
    if (base >= nRows) return;

    float4 Wr[16];
    const float4* W4 = (const float4*)(W + lane * DIM);
    #pragma unroll
    for (int j = 0; j < 16; ++j) Wr[j] = W4[j];

    const float4* src = (const float4*)entity_emb;
    #pragma unroll
    for (int i = 0; i < 2; ++i) {
        const int idx = i * 64 + lane;
        const int row = base + (idx >> 4);
        const size_t g = (row < nRows) ? ((size_t)base * 16 + idx) : 0;
        xs[idx] = src[g];
    }
    asm volatile("s_waitcnt lgkmcnt(0)" ::: "memory");

    #pragma unroll
    for (int r = 0; r < 8; ++r) {
        const int row = base + r;
        if (row >= nRows) break;
        float h0 = 0.f, h1 = 0.f, h2 = 0.f, h3 = 0.f;
        #pragma unroll
        for (int jc = 0; jc < 16; jc += 4) {
            float4 a = xs[r * 16 + jc + 0];
            float4 b = xs[r * 16 + jc + 1];
            float4 c = xs[r * 16 + jc + 2];
            float4 d = xs[r * 16 + jc + 3];
            h0 += a.x*Wr[jc+0].x + a.y*Wr[jc+0].y + a.z*Wr[jc+0].z + a.w*Wr[jc+0].w;
            h1 += b.x*Wr[jc+1].x + b.y*Wr[jc+1].y + b.z*Wr[jc+1].z + b.w*Wr[jc+1].w;
            h2 += c.x*Wr[jc+2].x + c.y*Wr[jc+2].y + c.z*Wr[jc+2].z + c.w*Wr[jc+2].w;
            h3 += d.x*Wr[jc+3].x + d.y*Wr[jc+3].y + d.z*Wr[jc+3].z + d.w*Wr[jc+3].w;
        }
        WEb[(size_t)row * DIM + lane] = f2bf((h0 + h1) + (h2 + h3));
    }
}

// ============================================================================
// Kernel 2: main. One wave per pair (R7 shape, no barriers). Paired-dim
// gathers: lane l owns dims (2*(l&31), 2*(l&31)+1); each wave-load reads
// ushort2/lane so HALF-waves service two different WE rows per instruction
// -> per-pair gather VMEM count halved (~290 -> ~150).
// ============================================================================
__global__ __launch_bounds__(256, 4) void kgcn_main(
    const int* __restrict__ pairs,
    const int* __restrict__ adjE,
    const int* __restrict__ adjR,
    const unsigned short* __restrict__ WEb,
    const float* __restrict__ relation_emb,
    const float* __restrict__ user_emb,
    const float* __restrict__ W,
    const float* __restrict__ bias,
    float* __restrict__ out,
    int nPairs)
{
    __shared__ float ev1_s[4][KN * DIM];  // per-wave layer-0 outputs
    __shared__ float xb_s[4][DIM];        // per-wave matvec broadcast buffer

    const int tid  = threadIdx.x;
    const int wave = tid >> 6;
    const int lane = tid & 63;
    const int p    = blockIdx.x * 4 + wave;
    if (p >= nPairs) return;              // no barriers -> safe early-out

    float* ev1 = ev1_s[wave];
    float* xb  = xb_s[wave];

    const int h  = lane >> 5;             // half-wave id (0/1)
    const int c  = lane & 31;             // dword column within a WE row
    const int c2 = c * 2;                 // first owned dim

    const int user = pairs[2 * p + 0];
    const int item = pairs[2 * p + 1];

    const float2 b2 = *(const float2*)(bias + c2);
    const unsigned* WErow = (const unsigned*)WEb;   // row e starts at e*32 dwords

    // item adjacency row
    int rk0 = 0, e1 = 0;
    if (lane < KN) {
        rk0 = adjR[(size_t)item * KN + lane];
        e1  = adjE[(size_t)item * KN + lane];
    }

    // dot(u, rel_r) for all 32 relations: 2 lanes per relation
    float acc;
    {
        const int r = lane >> 1, hlf = lane & 1;
        const float4* rel4 = (const float4*)(relation_emb + r * DIM + hlf * 32);
        const float4* u4   = (const float4*)(user_emb + (size_t)user * DIM + hlf * 32);
        float a0 = 0.f, a1 = 0.f;
        #pragma unroll
        for (int j = 0; j < 8; j += 2) {
            float4 a = rel4[j],     b = u4[j];
            float4 cc = rel4[j + 1], d = u4[j + 1];
            a0 += a.x*b.x + a.y*b.y + a.z*b.z + a.w*b.w;
            a1 += cc.x*d.x + cc.y*d.y + cc.z*d.z + cc.w*d.w;
        }
        acc = a0 + a1;
        acc += __shfl_xor(acc, 1);
    }

    // softmax within 16-lane subgroups (4 independent groups per call)
    auto softmax16 = [&](float s) -> float {
        float mx = s;
        mx = fmaxf(mx, __shfl_xor(mx, 1));
        mx = fmaxf(mx, __shfl_xor(mx, 2));
        mx = fmaxf(mx, __shfl_xor(mx, 4));
        mx = fmaxf(mx, __shfl_xor(mx, 8));
        float e = __expf(s - mx);
        float ss = e;
        ss += __shfl_xor(ss, 1);
        ss += __shfl_xor(ss, 2);
        ss += __shfl_xor(ss, 4);
        ss += __shfl_xor(ss, 8);
        return e * frcp(ss);
    };

    const float w0 = softmax16(__shfl(acc, rk0 << 1));

    // hop-1 adjacency packed 4 rows/slot: slot s, subgroup m4 holds group
    // 4s+m4; lane m4*16+kk holds neighbor kk of that group.
    const int m4 = lane >> 4, kk = lane & 15;
    int ekA[4]; float wA[4];
    #pragma unroll
    for (int s = 0; s < 4; ++s) {
        const int g  = __shfl(e1, 4 * s + m4);
        const int rk = adjR[(size_t)(unsigned)g * KN + kk];
        ekA[s]       = adjE[(size_t)(unsigned)g * KN + kk];
        wA[s] = softmax16(__shfl(acc, rk << 1));
    }

    // ---- layer 0, hop 1: groups processed in pairs (m: half 0, m+1: half 1).
    // Each wave-load covers one neighbor row of BOTH groups. No cross-half
    // combine: each half accumulates its own group fully in paired dims.
    #pragma unroll 1
    for (int m = 0; m < KN; m += 2) {
        const int s    = m >> 2;
        const int subh = ((m & 3) + h) * 16;           // per-lane slot base
        const int gs   = __shfl(e1, m + h);            // self row (per half)
        unsigned sv = WErow[(size_t)(unsigned)gs * 32 + c];
        float ax = b2.x + bflo(sv);
        float ay = b2.y + bfhi(sv);
        #pragma unroll
        for (int k = 0; k < KN; ++k) {
            const int   e = __shfl(ekA[s], subh + k);
            const float w = __shfl(wA[s],  subh + k);
            unsigned v = WErow[(size_t)(unsigned)e * 32 + c];
            ax += w * bflo(v);
            ay += w * bfhi(v);
        }
        *(float2*)&ev1[(m + h) * DIM + c2] = make_float2(fmaxf(ax, 0.f), fmaxf(ay, 0.f));
    }

    // ---- hop 0, layer 0: 16 neighbors split 8/8 across halves, then combine
    float ax = 0.f, ay = 0.f;
    #pragma unroll
    for (int k = 0; k < 8; ++k) {
        const int   e = __shfl(e1, h * 8 + k);
        const float w = __shfl(w0, h * 8 + k);
        unsigned v = WErow[(size_t)(unsigned)e * 32 + c];
        ax += w * bflo(v);
        ay += w * bfhi(v);
    }
    ax += __shfl_xor(ax, 32);
    ay += __shfl_xor(ay, 32);
    {
        unsigned sv = WErow[(size_t)item * 32 + c];
        ax += bflo(sv) + b2.x;
        ay += bfhi(sv) + b2.y;
    }
    const float e0x = fmaxf(ax, 0.f), e0y = fmaxf(ay, 0.f);

    // ---- layer 1 aggregate: x1 = e0 + sum_k w0_k * ev1_k (LDS, half-split)
    asm volatile("s_waitcnt lgkmcnt(0)" ::: "memory");  // ev1 writes done (wave-local)
    float sx = 0.f, sy = 0.f;
    #pragma unroll
    for (int k = 0; k < 8; ++k) {
        const int   kg = h * 8 + k;
        const float w  = __shfl(w0, kg);
        float2 ev = *(const float2*)&ev1[kg * DIM + c2];
        sx += w * ev.x;
        sy += w * ev.y;
    }
    sx += __shfl_xor(sx, 32);
    sy += __shfl_xor(sy, 32);
    const float x1x = e0x + sx, x1y = e0y + sy;

    // ---- the ONE real matvec: h1 = W x1 + b, via LDS broadcast ----
    asm volatile("s_waitcnt lgkmcnt(0)" ::: "memory");
    if (h == 0) *(float2*)&xb[c2] = make_float2(x1x, x1y);
    asm volatile("s_waitcnt lgkmcnt(0)" ::: "memory");
    float h0 = bias[lane], h1 = 0.f, h2 = 0.f, h3 = 0.f;
    {
        const float4* Wl  = (const float4*)(W + lane * DIM);
        const float4* xv4 = (const float4*)xb;
        #pragma unroll
        for (int j = 0; j < 16; j += 4) {
            float4 w0v = Wl[j],   x0v = xv4[j];
            float4 w1v = Wl[j+1], x1v = xv4[j+1];
            float4 w2v = Wl[j+2], x2v = xv4[j+2];
            float4 w3v = Wl[j+3], x3v = xv4[j+3];
            h0 += w0v.x*x0v.x + w0v.y*x0v.y + w0v.z*x0v.z + w0v.w*x0v.w;
            h1 += w1v.x*x1v.x + w1v.y*x1v.y + w1v.z*x1v.z + w1v.w*x1v.w;
            h2 += w2v.x*x2v.x + w2v.y*x2v.y + w2v.z*x2v.z + w2v.w*x2v.w;
            h3 += w3v.x*x3v.x + w3v.y*x3v.y + w3v.z*x3v.z + w3v.w*x3v.w;
        }
    }
    const float itemf = tanhf((h0 + h1) + (h2 + h3));

    float d = user_emb[(size_t)user * DIM + lane] * itemf;
    d += __shfl_xor(d, 1);
    d += __shfl_xor(d, 2);
    d += __shfl_xor(d, 4);
    d += __shfl_xor(d, 8);
    d += __shfl_xor(d, 16);
    d += __shfl_xor(d, 32);
    if (lane == 0) out[p] = 1.f / (1.f + expf(-d));
}

// ============================================================================
// Fallback (verified R5 kernel) in case ws_size < WE table size.
// ============================================================================
__global__ __launch_bounds__(256, 4) void kgcn_fallback(
    const int* __restrict__ pairs, const int* __restrict__ adj_entity,
    const int* __restrict__ adj_relation, const float* __restrict__ entity_emb,
    const float* __restrict__ relation_emb, const float* __restrict__ user_emb,
    const float* __restrict__ W, const float* __restrict__ bias,
    float* __restrict__ out, int nPairs)
{
    __shared__ float ev1_s[2][KN * DIM];
    __shared__ float xb_s[4][DIM];
    const int tid = threadIdx.x, wave = tid >> 6, lane = tid & 63;
    const int q = wave >> 1, half = wave & 1;
    int p = blockIdx.x * 2 + q;
    if (p >= nPairs) p = nPairs - 1;
    float* ev1 = ev1_s[q]; float* xb = xb_s[wave];
    const int user = pairs[2 * p + 0], item = pairs[2 * p + 1];
    const float bval = bias[lane];
    const float* emb_l = entity_emb + lane;
    const float4* W4 = (const float4*)(W + lane * DIM);
    int rk0 = 0, e1 = 0;
    if (lane < KN) {
        rk0 = adj_relation[(size_t)item * KN + lane];
        e1  = adj_entity[(size_t)item * KN + lane];
    }
    float acc;
    {
        const int r = lane >> 1, hlf = lane & 1;
        const float4* rel4 = (const float4*)(relation_emb + r * DIM + hlf * 32);
        const float4* u4 = (const float4*)(user_emb + (size_t)user * DIM + hlf * 32);
        float a0 = 0.f, a1 = 0.f;
        #pragma unroll
        for (int j = 0; j < 8; j += 2) {
            float4 a = rel4[j], b = u4[j], c = rel4[j+1], d = u4[j+1];
            a0 += a.x*b.x + a.y*b.y + a.z*b.z + a.w*b.w;
            a1 += c.x*d.x + c.y*d.y + c.z*d.z + c.w*d.w;
        }
        acc = a0 + a1; acc += __shfl_xor(acc, 1);
    }
    auto softmax16 = [&](float s) -> float {
        float mx = s;
        mx = fmaxf(mx, __shfl_xor(mx, 1)); mx = fmaxf(mx, __shfl_xor(mx, 2));
        mx = fmaxf(mx, __shfl_xor(mx, 4)); mx = fmaxf(mx, __shfl_xor(mx, 8));
        float e = __expf(s - mx);
        float ss = e;
        ss += __shfl_xor(ss, 1); ss += __shfl_xor(ss, 2);
        ss += __shfl_xor(ss, 4); ss += __shfl_xor(ss, 8);
        return e * frcp(ss);
    };
    auto matvec = [&](float xv) -> float {
        asm volatile("s_waitcnt lgkmcnt(0)" ::: "memory");
        xb[lane] = xv;
        asm volatile("s_waitcnt lgkmcnt(0)" ::: "memory");
        float h0 = bval, h1 = 0.f, h2 = 0.f, h3 = 0.f;
        const float4* xv4 = (const float4*)xb;
        #pragma unroll
        for (int j = 0; j < 16; j += 4) {
            float4 w0 = W4[j], x0 = xv4[j], w1 = W4[j+1], x1 = xv4[j+1];
            float4 w2 = W4[j+2], x2 = xv4[j+2], w3 = W4[j+3], x3 = xv4[j+3];
            h0 += w0.x*x0.x + w0.y*x0.y + w0.z*x0.z + w0.w*x0.w;
            h1 += w1.x*x1.x + w1.y*x1.y + w1.z*x1.z + w1.w*x1.w;
            h2 += w2.x*x2.x + w2.y*x2.y + w2.z*x2.z + w2.w*x2.w;
            h3 += w3.x*x3.x + w3.y*x3.y + w3.z*x3.z + w3.w*x3.w;
        }
        return (h0 + h1) + (h2 + h3);
    };
    auto gather = [&](int self, int ek, float w) -> float {
        float xa = emb_l[(size_t)(unsigned)self * DIM], xc = 0.f;
        #pragma unroll
        for (int k = 0; k < KN; k += 2) {
            const int e0i = __shfl(ek, k); const float f0 = __shfl(w, k);
            const int e1i = __shfl(ek, k + 1); const float f1 = __shfl(w, k + 1);
            xa += f0 * emb_l[(size_t)(unsigned)e0i * DIM];
            xc += f1 * emb_l[(size_t)(unsigned)e1i * DIM];
        }
        return xa + xc;
    };
    int rk_n = 0, ek_n = 0;
    {
        const int g0 = __shfl(e1, half * 8);
        if (lane < KN) {
            rk_n = adj_relation[(size_t)(unsigned)g0 * KN + lane];
            ek_n = adj_entity[(size_t)(unsigned)g0 * KN + lane];
        }
    }
    #pragma unroll 1
    for (int mi = 0; mi < 8; ++mi) {
        const int m = half * 8 + mi;
        const int g = __shfl(e1, m);
        const int rk = rk_n, ek = ek_n;
        if (mi + 1 < 8) {
            const int gn = __shfl(e1, m + 1);
            if (lane < KN) {
                rk_n = adj_relation[(size_t)(unsigned)gn * KN + lane];
                ek_n = adj_entity[(size_t)(unsigned)gn * KN + lane];
            }
        }
        const float w = softmax16(__shfl(acc, rk << 1));
        const float x = gather(g, ek, w);
        ev1[m * DIM + lane] = fmaxf(matvec(x), 0.f);
    }
    __syncthreads();
    if (half != 0) return;
    const float w0 = softmax16(__shfl(acc, rk0 << 1));
    const float x0 = gather(item, e1, w0);
    const float e0 = fmaxf(matvec(x0), 0.f);
    float xa = e0, xc = 0.f;
    #pragma unroll
    for (int k = 0; k < KN; k += 2) {
        xa += __shfl(w0, k) * ev1[k * DIM + lane];
        xc += __shfl(w0, k + 1) * ev1[(k + 1) * DIM + lane];
    }
    const float itemf = tanhf(matvec(xa + xc));
    float d = user_emb[(size_t)user * DIM + lane] * itemf;
    d += __shfl_xor(d, 1); d += __shfl_xor(d, 2); d += __shfl_xor(d, 4);
    d += __shfl_xor(d, 8); d += __shfl_xor(d, 16); d += __shfl_xor(d, 32);
    if (lane == 0) out[p] = 1.f / (1.f + expf(-d));
}

extern "C" void kernel_launch(void* const* d_in, const int* in_sizes, int n_in,
                              void* d_out, int out_size, void* d_ws, size_t ws_size,
                              hipStream_t stream) {
    const int*   pairs        = (const int*)d_in[0];
    const int*   adj_entity   = (const int*)d_in[1];
    const int*   adj_relation = (const int*)d_in[2];
    const float* entity_emb   = (const float*)d_in[3];
    const float* relation_emb = (const float*)d_in[4];
    const float* user_emb     = (const float*)d_in[5];
    const float* W            = (const float*)d_in[6];
    const float* b            = (const float*)d_in[7];
    float* out = (float*)d_out;

    const int nPairs = in_sizes[0] / 2;          // pairs is (B, 2)
    const int nEnt   = in_sizes[3] / DIM;        // entity count
    const size_t weBytes = (size_t)in_sizes[3] * sizeof(unsigned short);

    if (ws_size >= weBytes) {
        unsigned short* WEb = (unsigned short*)d_ws;
        const int preBlocks = (nEnt + 8 * 4 - 1) / (8 * 4);   // 8 rows/wave
        we_kernel<<<preBlocks, 256, 0, stream>>>(entity_emb, W, WEb, nEnt);
        const int mainBlocks = (nPairs + 3) / 4;              // 1 wave/pair
        kgcn_main<<<mainBlocks, 256, 0, stream>>>(pairs, adj_entity, adj_relation,
                                                  WEb, relation_emb, user_emb,
                                                  W, b, out, nPairs);
    } else {
        const int nBlocks = (nPairs + 1) / 2;
        kgcn_fallback<<<nBlocks, 256, 0, stream>>>(pairs, adj_entity, adj_relation,
                                                   entity_emb, relation_emb, user_emb,
                                                   W, b, out, nPairs);
    }
}

// Round 10
// 147.268 us; speedup vs baseline: 1.0880x; 1.0022x over previous
//
#include <hip/hip_runtime.h>
#include <hip/hip_bf16.h>
#include <math.h>

#define DIM  64
#define KN   16
#define NREL 32

__device__ __forceinline__ float frcp(float x) { return __builtin_amdgcn_rcpf(x); }

__device__ __forceinline__ unsigned short f2bf(float f) {
    unsigned u = __float_as_uint(f);
    u = (u + 0x7fffu + ((u >> 16) & 1u)) >> 16;   // RNE
    return (unsigned short)u;
}
// bf16 pair packed in a dword: low ushort = even dim, high ushort = odd dim
__device__ __forceinline__ float bflo(unsigned v) { return __uint_as_float(v << 16); }
__device__ __forceinline__ float bfhi(unsigned v) { return __uint_as_float(v & 0xffff0000u); }

// ============================================================================
// Kernel 1: WEb[e][d] = bf16( sum_j W[d][j] * entity_emb[e][j] )  (unchanged)
// ============================================================================
__global__ __launch_bounds__(256, 4) void we_kernel(
    const float* __restrict__ entity_emb,
    const float* __restrict__ W,
    unsigned short* __restrict__ WEb,
    int nRows)
{
    __shared__ float4 xs_s[4][8 * 16];
    const int tid  = threadIdx.x;
    const int wave = tid >> 6;
    const int lane = tid & 63;
    float4* xs = xs_s[wave];

    const int base = (blockIdx.x * 4 + wave) * 8;
    if (base >= nRows) return;

    float4 Wr[16];
    const float4* W4 = (const float4*)(W + lane * DIM);
    #pragma unroll
    for (int j = 0; j < 16; ++j) Wr[j] = W4[j];

    const float4* src = (const float4*)entity_emb;
    #pragma unroll
    for (int i = 0; i < 2; ++i) {
        const int idx = i * 64 + lane;
        const int row = base + (idx >> 4);
        const size_t g = (row < nRows) ? ((size_t)base * 16 + idx) : 0;
        xs[idx] = src[g];
    }
    asm volatile("s_waitcnt lgkmcnt(0)" ::: "memory");

    #pragma unroll
    for (int r = 0; r < 8; ++r) {
        const int row = base + r;
        if (row >= nRows) break;
        float h0 = 0.f, h1 = 0.f, h2 = 0.f, h3 = 0.f;
        #pragma unroll
        for (int jc = 0; jc < 16; jc += 4) {
            float4 a = xs[r * 16 + jc + 0];
            float4 b = xs[r * 16 + jc + 1];
            float4 c = xs[r * 16 + jc + 2];
            float4 d = xs[r * 16 + jc + 3];
            h0 += a.x*Wr[jc+0].x + a.y*Wr[jc+0].y + a.z*Wr[jc+0].z + a.w*Wr[jc+0].w;
            h1 += b.x*Wr[jc+1].x + b.y*Wr[jc+1].y + b.z*Wr[jc+1].z + b.w*Wr[jc+1].w;
            h2 += c.x*Wr[jc+2].x + c.y*Wr[jc+2].y + c.z*Wr[jc+2].z + c.w*Wr[jc+2].w;
            h3 += d.x*Wr[jc+3].x + d.y*Wr[jc+3].y + d.z*Wr[jc+3].z + d.w*Wr[jc+3].w;
        }
        WEb[(size_t)row * DIM + lane] = f2bf((h0 + h1) + (h2 + h3));
    }
}

// ============================================================================
// Kernel 2: main. One wave per pair, no barriers. FOUR dims per lane
// (uint2 = 4 bf16), 16 lanes per WE row -> each wave-load services FOUR
// rows (quarter-waves own different rows). Per-pair gather VMEM ~80.
// ============================================================================
__global__ __launch_bounds__(256, 4) void kgcn_main(
    const int* __restrict__ pairs,
    const int* __restrict__ adjE,
    const int* __restrict__ adjR,
    const unsigned short* __restrict__ WEb,
    const float* __restrict__ relation_emb,
    const float* __restrict__ user_emb,
    const float* __restrict__ W,
    const float* __restrict__ bias,
    float* __restrict__ out,
    int nPairs)
{
    __shared__ float ev1_s[4][KN * DIM];  // per-wave layer-0 outputs
    __shared__ float xb_s[4][DIM];        // per-wave matvec broadcast buffer

    const int tid  = threadIdx.x;
    const int wave = tid >> 6;
    const int lane = tid & 63;
    const int p    = blockIdx.x * 4 + wave;
    if (p >= nPairs) return;              // no barriers -> safe early-out

    float* ev1 = ev1_s[wave];
    float* xb  = xb_s[wave];

    const int qq = lane >> 4;             // quarter-wave id (0..3)
    const int c  = lane & 15;             // uint2 column within a WE row
    const int c4 = c * 4;                 // first owned dim

    const int user = pairs[2 * p + 0];
    const int item = pairs[2 * p + 1];

    const float4 b4 = *(const float4*)(bias + c4);
    const uint2* WEq = (const uint2*)WEb;   // row e starts at e*16 uint2

    // item adjacency row
    int rk0 = 0, e1 = 0;
    if (lane < KN) {
        rk0 = adjR[(size_t)item * KN + lane];
        e1  = adjE[(size_t)item * KN + lane];
    }

    // dot(u, rel_r) for all 32 relations: 2 lanes per relation
    float acc;
    {
        const int r = lane >> 1, hlf = lane & 1;
        const float4* rel4 = (const float4*)(relation_emb + r * DIM + hlf * 32);
        const float4* u4   = (const float4*)(user_emb + (size_t)user * DIM + hlf * 32);
        float a0 = 0.f, a1 = 0.f;
        #pragma unroll
        for (int j = 0; j < 8; j += 2) {
            float4 a = rel4[j],      b = u4[j];
            float4 cc = rel4[j + 1], d = u4[j + 1];
            a0 += a.x*b.x + a.y*b.y + a.z*b.z + a.w*b.w;
            a1 += cc.x*d.x + cc.y*d.y + cc.z*d.z + cc.w*d.w;
        }
        acc = a0 + a1;
        acc += __shfl_xor(acc, 1);
    }

    // softmax within 16-lane subgroups (4 independent groups per call)
    auto softmax16 = [&](float s) -> float {
        float mx = s;
        mx = fmaxf(mx, __shfl_xor(mx, 1));
        mx = fmaxf(mx, __shfl_xor(mx, 2));
        mx = fmaxf(mx, __shfl_xor(mx, 4));
        mx = fmaxf(mx, __shfl_xor(mx, 8));
        float e = __expf(s - mx);
        float ss = e;
        ss += __shfl_xor(ss, 1);
        ss += __shfl_xor(ss, 2);
        ss += __shfl_xor(ss, 4);
        ss += __shfl_xor(ss, 8);
        return e * frcp(ss);
    };

    const float w0 = softmax16(__shfl(acc, rk0 << 1));

    // hop-1 adjacency packed 4 rows/slot: slot s, subgroup m4 (= lane>>4)
    // holds group 4s+m4; lane m4*16+kk holds neighbor kk of that group.
    const int kk = c;
    int ekA[4]; float wA[4];
    #pragma unroll
    for (int s = 0; s < 4; ++s) {
        const int g  = __shfl(e1, 4 * s + qq);
        const int rk = adjR[(size_t)(unsigned)g * KN + kk];
        ekA[s]       = adjE[(size_t)(unsigned)g * KN + kk];
        wA[s] = softmax16(__shfl(acc, rk << 1));
    }

    // ---- layer 0, hop 1: 4 groups per outer iter (quarter qq owns group
    // 4s+qq); each wave-load covers one neighbor row of all 4 groups.
    // Group 4s+qq's neighbors live exactly in quarter qq's lanes of slot s.
    #pragma unroll 1
    for (int s = 0; s < 4; ++s) {
        const int gm = 4 * s + qq;
        const int gs = __shfl(e1, gm);            // self row (per quarter)
        uint2 sv = WEq[(size_t)(unsigned)gs * 16 + c];
        float ax = b4.x + bflo(sv.x);
        float ay = b4.y + bfhi(sv.x);
        float az = b4.z + bflo(sv.y);
        float aw = b4.w + bfhi(sv.y);
        #pragma unroll
        for (int k = 0; k < KN; ++k) {
            const int   e = __shfl(ekA[s], qq * 16 + k);
            const float w = __shfl(wA[s],  qq * 16 + k);
            uint2 v = WEq[(size_t)(unsigned)e * 16 + c];
            ax += w * bflo(v.x);
            ay += w * bfhi(v.x);
            az += w * bflo(v.y);
            aw += w * bfhi(v.y);
        }
        *(float4*)&ev1[gm * DIM + c4] =
            make_float4(fmaxf(ax, 0.f), fmaxf(ay, 0.f), fmaxf(az, 0.f), fmaxf(aw, 0.f));
    }

    // ---- hop 0, layer 0: 16 neighbors split 4/4/4/4 across quarters.
    // Lanes c, c+16, c+32, c+48 own the SAME dims -> xor-16/32 combine aligns.
    float ax = 0.f, ay = 0.f, az = 0.f, aw = 0.f;
    #pragma unroll
    for (int k = 0; k < 4; ++k) {
        const int   e = __shfl(e1, qq * 4 + k);
        const float w = __shfl(w0, qq * 4 + k);
        uint2 v = WEq[(size_t)(unsigned)e * 16 + c];
        ax += w * bflo(v.x);
        ay += w * bfhi(v.x);
        az += w * bflo(v.y);
        aw += w * bfhi(v.y);
    }
    ax += __shfl_xor(ax, 16); ay += __shfl_xor(ay, 16);
    az += __shfl_xor(az, 16); aw += __shfl_xor(aw, 16);
    ax += __shfl_xor(ax, 32); ay += __shfl_xor(ay, 32);
    az += __shfl_xor(az, 32); aw += __shfl_xor(aw, 32);
    {
        uint2 sv = WEq[(size_t)item * 16 + c];
        ax += bflo(sv.x) + b4.x;
        ay += bfhi(sv.x) + b4.y;
        az += bflo(sv.y) + b4.z;
        aw += bfhi(sv.y) + b4.w;
    }
    const float e0x = fmaxf(ax, 0.f), e0y = fmaxf(ay, 0.f);
    const float e0z = fmaxf(az, 0.f), e0w = fmaxf(aw, 0.f);

    // ---- layer 1 aggregate: x1 = e0 + sum_k w0_k * ev1_k (quarter-split)
    asm volatile("s_waitcnt lgkmcnt(0)" ::: "memory");  // ev1 writes done (wave-local)
    float sx = 0.f, sy = 0.f, sz = 0.f, sw = 0.f;
    #pragma unroll
    for (int k = 0; k < 4; ++k) {
        const int   kg = qq * 4 + k;
        const float w  = __shfl(w0, kg);
        float4 ev = *(const float4*)&ev1[kg * DIM + c4];
        sx += w * ev.x;
        sy += w * ev.y;
        sz += w * ev.z;
        sw += w * ev.w;
    }
    sx += __shfl_xor(sx, 16); sy += __shfl_xor(sy, 16);
    sz += __shfl_xor(sz, 16); sw += __shfl_xor(sw, 16);
    sx += __shfl_xor(sx, 32); sy += __shfl_xor(sy, 32);
    sz += __shfl_xor(sz, 32); sw += __shfl_xor(sw, 32);

    // ---- the ONE real matvec: h1 = W x1 + b, via LDS broadcast ----
    asm volatile("s_waitcnt lgkmcnt(0)" ::: "memory");
    if (qq == 0)
        *(float4*)&xb[c4] = make_float4(e0x + sx, e0y + sy, e0z + sz, e0w + sw);
    asm volatile("s_waitcnt lgkmcnt(0)" ::: "memory");
    float h0 = bias[lane], h1 = 0.f, h2 = 0.f, h3 = 0.f;
    {
        const float4* Wl  = (const float4*)(W + lane * DIM);
        const float4* xv4 = (const float4*)xb;
        #pragma unroll
        for (int j = 0; j < 16; j += 4) {
            float4 w0v = Wl[j],   x0v = xv4[j];
            float4 w1v = Wl[j+1], x1v = xv4[j+1];
            float4 w2v = Wl[j+2], x2v = xv4[j+2];
            float4 w3v = Wl[j+3], x3v = xv4[j+3];
            h0 += w0v.x*x0v.x + w0v.y*x0v.y + w0v.z*x0v.z + w0v.w*x0v.w;
            h1 += w1v.x*x1v.x + w1v.y*x1v.y + w1v.z*x1v.z + w1v.w*x1v.w;
            h2 += w2v.x*x2v.x + w2v.y*x2v.y + w2v.z*x2v.z + w2v.w*x2v.w;
            h3 += w3v.x*x3v.x + w3v.y*x3v.y + w3v.z*x3v.z + w3v.w*x3v.w;
        }
    }
    const float itemf = tanhf((h0 + h1) + (h2 + h3));

    float d = user_emb[(size_t)user * DIM + lane] * itemf;
    d += __shfl_xor(d, 1);
    d += __shfl_xor(d, 2);
    d += __shfl_xor(d, 4);
    d += __shfl_xor(d, 8);
    d += __shfl_xor(d, 16);
    d += __shfl_xor(d, 32);
    if (lane == 0) out[p] = 1.f / (1.f + expf(-d));
}

// ============================================================================
// Fallback (verified R5 kernel) in case ws_size < WE table size.
// ============================================================================
__global__ __launch_bounds__(256, 4) void kgcn_fallback(
    const int* __restrict__ pairs, const int* __restrict__ adj_entity,
    const int* __restrict__ adj_relation, const float* __restrict__ entity_emb,
    const float* __restrict__ relation_emb, const float* __restrict__ user_emb,
    const float* __restrict__ W, const float* __restrict__ bias,
    float* __restrict__ out, int nPairs)
{
    __shared__ float ev1_s[2][KN * DIM];
    __shared__ float xb_s[4][DIM];
    const int tid = threadIdx.x, wave = tid >> 6, lane = tid & 63;
    const int q = wave >> 1, half = wave & 1;
    int p = blockIdx.x * 2 + q;
    if (p >= nPairs) p = nPairs - 1;
    float* ev1 = ev1_s[q]; float* xb = xb_s[wave];
    const int user = pairs[2 * p + 0], item = pairs[2 * p + 1];
    const float bval = bias[lane];
    const float* emb_l = entity_emb + lane;
    const float4* W4 = (const float4*)(W + lane * DIM);
    int rk0 = 0, e1 = 0;
    if (lane < KN) {
        rk0 = adj_relation[(size_t)item * KN + lane];
        e1  = adj_entity[(size_t)item * KN + lane];
    }
    float acc;
    {
        const int r = lane >> 1, hlf = lane & 1;
        const float4* rel4 = (const float4*)(relation_emb + r * DIM + hlf * 32);
        const float4* u4 = (const float4*)(user_emb + (size_t)user * DIM + hlf * 32);
        float a0 = 0.f, a1 = 0.f;
        #pragma unroll
        for (int j = 0; j < 8; j += 2) {
            float4 a = rel4[j], b = u4[j], c = rel4[j+1], d = u4[j+1];
            a0 += a.x*b.x + a.y*b.y + a.z*b.z + a.w*b.w;
            a1 += c.x*d.x + c.y*d.y + c.z*d.z + c.w*d.w;
        }
        acc = a0 + a1; acc += __shfl_xor(acc, 1);
    }
    auto softmax16 = [&](float s) -> float {
        float mx = s;
        mx = fmaxf(mx, __shfl_xor(mx, 1)); mx = fmaxf(mx, __shfl_xor(mx, 2));
        mx = fmaxf(mx, __shfl_xor(mx, 4)); mx = fmaxf(mx, __shfl_xor(mx, 8));
        float e = __expf(s - mx);
        float ss = e;
        ss += __shfl_xor(ss, 1); ss += __shfl_xor(ss, 2);
        ss += __shfl_xor(ss, 4); ss += __shfl_xor(ss, 8);
        return e * frcp(ss);
    };
    auto matvec = [&](float xv) -> float {
        asm volatile("s_waitcnt lgkmcnt(0)" ::: "memory");
        xb[lane] = xv;
        asm volatile("s_waitcnt lgkmcnt(0)" ::: "memory");
        float h0 = bval, h1 = 0.f, h2 = 0.f, h3 = 0.f;
        const float4* xv4 = (const float4*)xb;
        #pragma unroll
        for (int j = 0; j < 16; j += 4) {
            float4 w0 = W4[j], x0 = xv4[j], w1 = W4[j+1], x1 = xv4[j+1];
            float4 w2 = W4[j+2], x2 = xv4[j+2], w3 = W4[j+3], x3 = xv4[j+3];
            h0 += w0.x*x0.x + w0.y*x0.y + w0.z*x0.z + w0.w*x0.w;
            h1 += w1.x*x1.x + w1.y*x1.y + w1.z*x1.z + w1.w*x1.w;
            h2 += w2.x*x2.x + w2.y*x2.y + w2.z*x2.z + w2.w*x2.w;
            h3 += w3.x*x3.x + w3.y*x3.y + w3.z*x3.z + w3.w*x3.w;
        }
        return (h0 + h1) + (h2 + h3);
    };
    auto gather = [&](int self, int ek, float w) -> float {
        float xa = emb_l[(size_t)(unsigned)self * DIM], xc = 0.f;
        #pragma unroll
        for (int k = 0; k < KN; k += 2) {
            const int e0i = __shfl(ek, k); const float f0 = __shfl(w, k);
            const int e1i = __shfl(ek, k + 1); const float f1 = __shfl(w, k + 1);
            xa += f0 * emb_l[(size_t)(unsigned)e0i * DIM];
            xc += f1 * emb_l[(size_t)(unsigned)e1i * DIM];
        }
        return xa + xc;
    };
    int rk_n = 0, ek_n = 0;
    {
        const int g0 = __shfl(e1, half * 8);
        if (lane < KN) {
            rk_n = adj_relation[(size_t)(unsigned)g0 * KN + lane];
            ek_n = adj_entity[(size_t)(unsigned)g0 * KN + lane];
        }
    }
    #pragma unroll 1
    for (int mi = 0; mi < 8; ++mi) {
        const int m = half * 8 + mi;
        const int g = __shfl(e1, m);
        const int rk = rk_n, ek = ek_n;
        if (mi + 1 < 8) {
            const int gn = __shfl(e1, m + 1);
            if (lane < KN) {
                rk_n = adj_relation[(size_t)(unsigned)gn * KN + lane];
                ek_n = adj_entity[(size_t)(unsigned)gn * KN + lane];
            }
        }
        const float w = softmax16(__shfl(acc, rk << 1));
        const float x = gather(g, ek, w);
        ev1[m * DIM + lane] = fmaxf(matvec(x), 0.f);
    }
    __syncthreads();
    if (half != 0) return;
    const float w0 = softmax16(__shfl(acc, rk0 << 1));
    const float x0 = gather(item, e1, w0);
    const float e0 = fmaxf(matvec(x0), 0.f);
    float xa = e0, xc = 0.f;
    #pragma unroll
    for (int k = 0; k < KN; k += 2) {
        xa += __shfl(w0, k) * ev1[k * DIM + lane];
        xc += __shfl(w0, k + 1) * ev1[(k + 1) * DIM + lane];
    }
    const float itemf = tanhf(matvec(xa + xc));
    float d = user_emb[(size_t)user * DIM + lane] * itemf;
    d += __shfl_xor(d, 1); d += __shfl_xor(d, 2); d += __shfl_xor(d, 4);
    d += __shfl_xor(d, 8); d += __shfl_xor(d, 16); d += __shfl_xor(d, 32);
    if (lane == 0) out[p] = 1.f / (1.f + expf(-d));
}

extern "C" void kernel_launch(void* const* d_in, const int* in_sizes, int n_in,
                              void* d_out, int out_size, void* d_ws, size_t ws_size,
                              hipStream_t stream) {
    const int*   pairs        = (const int*)d_in[0];
    const int*   adj_entity   = (const int*)d_in[1];
    const int*   adj_relation = (const int*)d_in[2];
    const float* entity_emb   = (const float*)d_in[3];
    const float* relation_emb = (const float*)d_in[4];
    const float* user_emb     = (const float*)d_in[5];
    const float* W            = (const float*)d_in[6];
    const float* b            = (const float*)d_in[7];
    float* out = (float*)d_out;

    const int nPairs = in_sizes[0] / 2;          // pairs is (B, 2)
    const int nEnt   = in_sizes[3] / DIM;        // entity count
    const size_t weBytes = (size_t)in_sizes[3] * sizeof(unsigned short);

    if (ws_size >= weBytes) {
        unsigned short* WEb = (unsigned short*)d_ws;
        const int preBlocks = (nEnt + 8 * 4 - 1) / (8 * 4);   // 8 rows/wave
        we_kernel<<<preBlocks, 256, 0, stream>>>(entity_emb, W, WEb, nEnt);
        const int mainBlocks = (nPairs + 3) / 4;              // 1 wave/pair
        kgcn_main<<<mainBlocks, 256, 0, stream>>>(pairs, adj_entity, adj_relation,
                                                  WEb, relation_emb, user_emb,
                                                  W, b, out, nPairs);
    } else {
        const int nBlocks = (nPairs + 1) / 2;
        kgcn_fallback<<<nBlocks, 256, 0, stream>>>(pairs, adj_entity, adj_relation,
                                                   entity_emb, relation_emb, user_emb,
                                                   W, b, out, nPairs);
    }
}

// Round 11
// 147.187 us; speedup vs baseline: 1.0886x; 1.0005x over previous
//
#include <hip/hip_runtime.h>
#include <hip/hip_bf16.h>
#include <math.h>

#define DIM  64
#define KN   16
#define NREL 32

__device__ __forceinline__ float frcp(float x) { return __builtin_amdgcn_rcpf(x); }

__device__ __forceinline__ unsigned short f2bf(float f) {
    unsigned u = __float_as_uint(f);
    u = (u + 0x7fffu + ((u >> 16) & 1u)) >> 16;   // RNE
    return (unsigned short)u;
}
// bf16 pair packed in a dword: low ushort = even dim, high ushort = odd dim
__device__ __forceinline__ float bflo(unsigned v) { return __uint_as_float(v << 16); }
__device__ __forceinline__ float bfhi(unsigned v) { return __uint_as_float(v & 0xffff0000u); }

// ============================================================================
// Kernel 1: WEb[e][d] = bf16( sum_j W[d][j] * entity_emb[e][j] )  (unchanged)
// ============================================================================
__global__ __launch_bounds__(256, 4) void we_kernel(
    const float* __restrict__ entity_emb,
    const float* __restrict__ W,
    unsigned short* __restrict__ WEb,
    int nRows)
{
    __shared__ float4 xs_s[4][8 * 16];
    const int tid  = threadIdx.x;
    const int wave = tid >> 6;
    const int lane = tid & 63;
    float4* xs = xs_s[wave];

    const int base = (blockIdx.x * 4 + wave) * 8;
    if (base >= nRows) return;

    float4 Wr[16];
    const float4* W4 = (const float4*)(W + lane * DIM);
    #pragma unroll
    for (int j = 0; j < 16; ++j) Wr[j] = W4[j];

    const float4* src = (const float4*)entity_emb;
    #pragma unroll
    for (int i = 0; i < 2; ++i) {
        const int idx = i * 64 + lane;
        const int row = base + (idx >> 4);
        const size_t g = (row < nRows) ? ((size_t)base * 16 + idx) : 0;
        xs[idx] = src[g];
    }
    asm volatile("s_waitcnt lgkmcnt(0)" ::: "memory");

    #pragma unroll
    for (int r = 0; r < 8; ++r) {
        const int row = base + r;
        if (row >= nRows) break;
        float h0 = 0.f, h1 = 0.f, h2 = 0.f, h3 = 0.f;
        #pragma unroll
        for (int jc = 0; jc < 16; jc += 4) {
            float4 a = xs[r * 16 + jc + 0];
            float4 b = xs[r * 16 + jc + 1];
            float4 c = xs[r * 16 + jc + 2];
            float4 d = xs[r * 16 + jc + 3];
            h0 += a.x*Wr[jc+0].x + a.y*Wr[jc+0].y + a.z*Wr[jc+0].z + a.w*Wr[jc+0].w;
            h1 += b.x*Wr[jc+1].x + b.y*Wr[jc+1].y + b.z*Wr[jc+1].z + b.w*Wr[jc+1].w;
            h2 += c.x*Wr[jc+2].x + c.y*Wr[jc+2].y + c.z*Wr[jc+2].z + c.w*Wr[jc+2].w;
            h3 += d.x*Wr[jc+3].x + d.y*Wr[jc+3].y + d.z*Wr[jc+3].z + d.w*Wr[jc+3].w;
        }
        WEb[(size_t)row * DIM + lane] = f2bf((h0 + h1) + (h2 + h3));
    }
}

// ============================================================================
// Kernel 2: main. One wave per pair, no barriers, 4 dims/lane (uint2).
// R11: deeper memory-level parallelism per wave — hop-0 loads hoisted ahead
// of the hop-1 loop, all slot-adjacency loads issued before softmaxes, and
// the gather loop unrolled 2x so ~34 loads are in flight instead of 17.
// ============================================================================
__global__ __launch_bounds__(256, 4) void kgcn_main(
    const int* __restrict__ pairs,
    const int* __restrict__ adjE,
    const int* __restrict__ adjR,
    const unsigned short* __restrict__ WEb,
    const float* __restrict__ relation_emb,
    const float* __restrict__ user_emb,
    const float* __restrict__ W,
    const float* __restrict__ bias,
    float* __restrict__ out,
    int nPairs)
{
    __shared__ float ev1_s[4][KN * DIM];  // per-wave layer-0 outputs
    __shared__ float xb_s[4][DIM];        // per-wave matvec broadcast buffer

    const int tid  = threadIdx.x;
    const int wave = tid >> 6;
    const int lane = tid & 63;
    const int p    = blockIdx.x * 4 + wave;
    if (p >= nPairs) return;              // no barriers -> safe early-out

    float* ev1 = ev1_s[wave];
    float* xb  = xb_s[wave];

    const int qq = lane >> 4;             // quarter-wave id (0..3)
    const int c  = lane & 15;             // uint2 column within a WE row
    const int c4 = c * 4;                 // first owned dim

    const int user = pairs[2 * p + 0];
    const int item = pairs[2 * p + 1];

    const float4 b4 = *(const float4*)(bias + c4);
    const uint2* WEq = (const uint2*)WEb;   // row e starts at e*16 uint2

    // item adjacency row
    int rk0 = 0, e1 = 0;
    if (lane < KN) {
        rk0 = adjR[(size_t)item * KN + lane];
        e1  = adjE[(size_t)item * KN + lane];
    }

    // dot(u, rel_r) for all 32 relations: 2 lanes per relation
    float acc;
    {
        const int r = lane >> 1, hlf = lane & 1;
        const float4* rel4 = (const float4*)(relation_emb + r * DIM + hlf * 32);
        const float4* u4   = (const float4*)(user_emb + (size_t)user * DIM + hlf * 32);
        float a0 = 0.f, a1 = 0.f;
        #pragma unroll
        for (int j = 0; j < 8; j += 2) {
            float4 a = rel4[j],      b = u4[j];
            float4 cc = rel4[j + 1], d = u4[j + 1];
            a0 += a.x*b.x + a.y*b.y + a.z*b.z + a.w*b.w;
            a1 += cc.x*d.x + cc.y*d.y + cc.z*d.z + cc.w*d.w;
        }
        acc = a0 + a1;
        acc += __shfl_xor(acc, 1);
    }

    // ---- EARLY independent loads: hop-0 gather rows (item self + 4
    // neighbors per quarter) stay in flight through the whole hop-1 phase.
    const uint2 itemv = WEq[(size_t)item * 16 + c];
    uint2 h0v[4];
    #pragma unroll
    for (int k = 0; k < 4; ++k) {
        const int e = __shfl(e1, qq * 4 + k);
        h0v[k] = WEq[(size_t)(unsigned)e * 16 + c];
    }

    // ---- slot adjacency: ALL loads first, then the dependent softmaxes ----
    int rkA[4], ekA[4];
    #pragma unroll
    for (int s = 0; s < 4; ++s) {
        const int g = __shfl(e1, 4 * s + qq);
        rkA[s] = adjR[(size_t)(unsigned)g * KN + c];
        ekA[s] = adjE[(size_t)(unsigned)g * KN + c];
    }

    // softmax within 16-lane subgroups (4 independent groups per call)
    auto softmax16 = [&](float s) -> float {
        float mx = s;
        mx = fmaxf(mx, __shfl_xor(mx, 1));
        mx = fmaxf(mx, __shfl_xor(mx, 2));
        mx = fmaxf(mx, __shfl_xor(mx, 4));
        mx = fmaxf(mx, __shfl_xor(mx, 8));
        float e = __expf(s - mx);
        float ss = e;
        ss += __shfl_xor(ss, 1);
        ss += __shfl_xor(ss, 2);
        ss += __shfl_xor(ss, 4);
        ss += __shfl_xor(ss, 8);
        return e * frcp(ss);
    };

    float wA[4];
    #pragma unroll
    for (int s = 0; s < 4; ++s) wA[s] = softmax16(__shfl(acc, rkA[s] << 1));
    const float w0 = softmax16(__shfl(acc, rk0 << 1));

    // ---- layer 0, hop 1: 4 groups per outer iter (quarter qq owns group
    // 4s+qq); unroll 2 => two iterations' loads (34) pipeline together.
    #pragma unroll 2
    for (int s = 0; s < 4; ++s) {
        const int gm = 4 * s + qq;
        const int gs = __shfl(e1, gm);            // self row (per quarter)
        uint2 sv = WEq[(size_t)(unsigned)gs * 16 + c];
        float ax = b4.x + bflo(sv.x);
        float ay = b4.y + bfhi(sv.x);
        float az = b4.z + bflo(sv.y);
        float aw = b4.w + bfhi(sv.y);
        #pragma unroll
        for (int k = 0; k < KN; ++k) {
            const int   e = __shfl(ekA[s], qq * 16 + k);
            const float w = __shfl(wA[s],  qq * 16 + k);
            uint2 v = WEq[(size_t)(unsigned)e * 16 + c];
            ax += w * bflo(v.x);
            ay += w * bfhi(v.x);
            az += w * bflo(v.y);
            aw += w * bfhi(v.y);
        }
        *(float4*)&ev1[gm * DIM + c4] =
            make_float4(fmaxf(ax, 0.f), fmaxf(ay, 0.f), fmaxf(az, 0.f), fmaxf(aw, 0.f));
    }

    // ---- hop 0, layer 0: accumulate the preloaded rows (4/4/4/4 split).
    // Lanes c, c+16, c+32, c+48 own the SAME dims -> xor-16/32 combine aligns.
    float ax = 0.f, ay = 0.f, az = 0.f, aw = 0.f;
    #pragma unroll
    for (int k = 0; k < 4; ++k) {
        const float w = __shfl(w0, qq * 4 + k);
        ax += w * bflo(h0v[k].x);
        ay += w * bfhi(h0v[k].x);
        az += w * bflo(h0v[k].y);
        aw += w * bfhi(h0v[k].y);
    }
    ax += __shfl_xor(ax, 16); ay += __shfl_xor(ay, 16);
    az += __shfl_xor(az, 16); aw += __shfl_xor(aw, 16);
    ax += __shfl_xor(ax, 32); ay += __shfl_xor(ay, 32);
    az += __shfl_xor(az, 32); aw += __shfl_xor(aw, 32);
    ax += bflo(itemv.x) + b4.x;
    ay += bfhi(itemv.x) + b4.y;
    az += bflo(itemv.y) + b4.z;
    aw += bfhi(itemv.y) + b4.w;
    const float e0x = fmaxf(ax, 0.f), e0y = fmaxf(ay, 0.f);
    const float e0z = fmaxf(az, 0.f), e0w = fmaxf(aw, 0.f);

    // ---- layer 1 aggregate: x1 = e0 + sum_k w0_k * ev1_k (quarter-split)
    asm volatile("s_waitcnt lgkmcnt(0)" ::: "memory");  // ev1 writes done (wave-local)
    float sx = 0.f, sy = 0.f, sz = 0.f, sw = 0.f;
    #pragma unroll
    for (int k = 0; k < 4; ++k) {
        const int   kg = qq * 4 + k;
        const float w  = __shfl(w0, kg);
        float4 ev = *(const float4*)&ev1[kg * DIM + c4];
        sx += w * ev.x;
        sy += w * ev.y;
        sz += w * ev.z;
        sw += w * ev.w;
    }
    sx += __shfl_xor(sx, 16); sy += __shfl_xor(sy, 16);
    sz += __shfl_xor(sz, 16); sw += __shfl_xor(sw, 16);
    sx += __shfl_xor(sx, 32); sy += __shfl_xor(sy, 32);
    sz += __shfl_xor(sz, 32); sw += __shfl_xor(sw, 32);

    // ---- the ONE real matvec: h1 = W x1 + b, via LDS broadcast ----
    asm volatile("s_waitcnt lgkmcnt(0)" ::: "memory");
    if (qq == 0)
        *(float4*)&xb[c4] = make_float4(e0x + sx, e0y + sy, e0z + sz, e0w + sw);
    asm volatile("s_waitcnt lgkmcnt(0)" ::: "memory");
    float h0 = bias[lane], h1 = 0.f, h2 = 0.f, h3 = 0.f;
    {
        const float4* Wl  = (const float4*)(W + lane * DIM);
        const float4* xv4 = (const float4*)xb;
        #pragma unroll
        for (int j = 0; j < 16; j += 4) {
            float4 w0v = Wl[j],   x0v = xv4[j];
            float4 w1v = Wl[j+1], x1v = xv4[j+1];
            float4 w2v = Wl[j+2], x2v = xv4[j+2];
            float4 w3v = Wl[j+3], x3v = xv4[j+3];
            h0 += w0v.x*x0v.x + w0v.y*x0v.y + w0v.z*x0v.z + w0v.w*x0v.w;
            h1 += w1v.x*x1v.x + w1v.y*x1v.y + w1v.z*x1v.z + w1v.w*x1v.w;
            h2 += w2v.x*x2v.x + w2v.y*x2v.y + w2v.z*x2v.z + w2v.w*x2v.w;
            h3 += w3v.x*x3v.x + w3v.y*x3v.y + w3v.z*x3v.z + w3v.w*x3v.w;
        }
    }
    const float itemf = tanhf((h0 + h1) + (h2 + h3));

    float d = user_emb[(size_t)user * DIM + lane] * itemf;
    d += __shfl_xor(d, 1);
    d += __shfl_xor(d, 2);
    d += __shfl_xor(d, 4);
    d += __shfl_xor(d, 8);
    d += __shfl_xor(d, 16);
    d += __shfl_xor(d, 32);
    if (lane == 0) out[p] = 1.f / (1.f + expf(-d));
}

// ============================================================================
// Fallback (verified R5 kernel) in case ws_size < WE table size.
// ============================================================================
__global__ __launch_bounds__(256, 4) void kgcn_fallback(
    const int* __restrict__ pairs, const int* __restrict__ adj_entity,
    const int* __restrict__ adj_relation, const float* __restrict__ entity_emb,
    const float* __restrict__ relation_emb, const float* __restrict__ user_emb,
    const float* __restrict__ W, const float* __restrict__ bias,
    float* __restrict__ out, int nPairs)
{
    __shared__ float ev1_s[2][KN * DIM];
    __shared__ float xb_s[4][DIM];
    const int tid = threadIdx.x, wave = tid >> 6, lane = tid & 63;
    const int q = wave >> 1, half = wave & 1;
    int p = blockIdx.x * 2 + q;
    if (p >= nPairs) p = nPairs - 1;
    float* ev1 = ev1_s[q]; float* xb = xb_s[wave];
    const int user = pairs[2 * p + 0], item = pairs[2 * p + 1];
    const float bval = bias[lane];
    const float* emb_l = entity_emb + lane;
    const float4* W4 = (const float4*)(W + lane * DIM);
    int rk0 = 0, e1 = 0;
    if (lane < KN) {
        rk0 = adj_relation[(size_t)item * KN + lane];
        e1  = adj_entity[(size_t)item * KN + lane];
    }
    float acc;
    {
        const int r = lane >> 1, hlf = lane & 1;
        const float4* rel4 = (const float4*)(relation_emb + r * DIM + hlf * 32);
        const float4* u4 = (const float4*)(user_emb + (size_t)user * DIM + hlf * 32);
        float a0 = 0.f, a1 = 0.f;
        #pragma unroll
        for (int j = 0; j < 8; j += 2) {
            float4 a = rel4[j], b = u4[j], c = rel4[j+1], d = u4[j+1];
            a0 += a.x*b.x + a.y*b.y + a.z*b.z + a.w*b.w;
            a1 += c.x*d.x + c.y*d.y + c.z*d.z + c.w*d.w;
        }
        acc = a0 + a1; acc += __shfl_xor(acc, 1);
    }
    auto softmax16 = [&](float s) -> float {
        float mx = s;
        mx = fmaxf(mx, __shfl_xor(mx, 1)); mx = fmaxf(mx, __shfl_xor(mx, 2));
        mx = fmaxf(mx, __shfl_xor(mx, 4)); mx = fmaxf(mx, __shfl_xor(mx, 8));
        float e = __expf(s - mx);
        float ss = e;
        ss += __shfl_xor(ss, 1); ss += __shfl_xor(ss, 2);
        ss += __shfl_xor(ss, 4); ss += __shfl_xor(ss, 8);
        return e * frcp(ss);
    };
    auto matvec = [&](float xv) -> float {
        asm volatile("s_waitcnt lgkmcnt(0)" ::: "memory");
        xb[lane] = xv;
        asm volatile("s_waitcnt lgkmcnt(0)" ::: "memory");
        float h0 = bval, h1 = 0.f, h2 = 0.f, h3 = 0.f;
        const float4* xv4 = (const float4*)xb;
        #pragma unroll
        for (int j = 0; j < 16; j += 4) {
            float4 w0 = W4[j], x0 = xv4[j], w1 = W4[j+1], x1 = xv4[j+1];
            float4 w2 = W4[j+2], x2 = xv4[j+2], w3 = W4[j+3], x3 = xv4[j+3];
            h0 += w0.x*x0.x + w0.y*x0.y + w0.z*x0.z + w0.w*x0.w;
            h1 += w1.x*x1.x + w1.y*x1.y + w1.z*x1.z + w1.w*x1.w;
            h2 += w2.x*x2.x + w2.y*x2.y + w2.z*x2.z + w2.w*x2.w;
            h3 += w3.x*x3.x + w3.y*x3.y + w3.z*x3.z + w3.w*x3.w;
        }
        return (h0 + h1) + (h2 + h3);
    };
    auto gather = [&](int self, int ek, float w) -> float {
        float xa = emb_l[(size_t)(unsigned)self * DIM], xc = 0.f;
        #pragma unroll
        for (int k = 0; k < KN; k += 2) {
            const int e0i = __shfl(ek, k); const float f0 = __shfl(w, k);
            const int e1i = __shfl(ek, k + 1); const float f1 = __shfl(w, k + 1);
            xa += f0 * emb_l[(size_t)(unsigned)e0i * DIM];
            xc += f1 * emb_l[(size_t)(unsigned)e1i * DIM];
        }
        return xa + xc;
    };
    int rk_n = 0, ek_n = 0;
    {
        const int g0 = __shfl(e1, half * 8);
        if (lane < KN) {
            rk_n = adj_relation[(size_t)(unsigned)g0 * KN + lane];
            ek_n = adj_entity[(size_t)(unsigned)g0 * KN + lane];
        }
    }
    #pragma unroll 1
    for (int mi = 0; mi < 8; ++mi) {
        const int m = half * 8 + mi;
        const int g = __shfl(e1, m);
        const int rk = rk_n, ek = ek_n;
        if (mi + 1 < 8) {
            const int gn = __shfl(e1, m + 1);
            if (lane < KN) {
                rk_n = adj_relation[(size_t)(unsigned)gn * KN + lane];
                ek_n = adj_entity[(size_t)(unsigned)gn * KN + lane];
            }
        }
        const float w = softmax16(__shfl(acc, rk << 1));
        const float x = gather(g, ek, w);
        ev1[m * DIM + lane] = fmaxf(matvec(x), 0.f);
    }
    __syncthreads();
    if (half != 0) return;
    const float w0 = softmax16(__shfl(acc, rk0 << 1));
    const float x0 = gather(item, e1, w0);
    const float e0 = fmaxf(matvec(x0), 0.f);
    float xa = e0, xc = 0.f;
    #pragma unroll
    for (int k = 0; k < KN; k += 2) {
        xa += __shfl(w0, k) * ev1[k * DIM + lane];
        xc += __shfl(w0, k + 1) * ev1[(k + 1) * DIM + lane];
    }
    const float itemf = tanhf(matvec(xa + xc));
    float d = user_emb[(size_t)user * DIM + lane] * itemf;
    d += __shfl_xor(d, 1); d += __shfl_xor(d, 2); d += __shfl_xor(d, 4);
    d += __shfl_xor(d, 8); d += __shfl_xor(d, 16); d += __shfl_xor(d, 32);
    if (lane == 0) out[p] = 1.f / (1.f + expf(-d));
}

extern "C" void kernel_launch(void* const* d_in, const int* in_sizes, int n_in,
                              void* d_out, int out_size, void* d_ws, size_t ws_size,
                              hipStream_t stream) {
    const int*   pairs        = (const int*)d_in[0];
    const int*   adj_entity   = (const int*)d_in[1];
    const int*   adj_relation = (const int*)d_in[2];
    const float* entity_emb   = (const float*)d_in[3];
    const float* relation_emb = (const float*)d_in[4];
    const float* user_emb     = (const float*)d_in[5];
    const float* W            = (const float*)d_in[6];
    const float* b            = (const float*)d_in[7];
    float* out = (float*)d_out;

    const int nPairs = in_sizes[0] / 2;          // pairs is (B, 2)
    const int nEnt   = in_sizes[3] / DIM;        // entity count
    const size_t weBytes = (size_t)in_sizes[3] * sizeof(unsigned short);

    if (ws_size >= weBytes) {
        unsigned short* WEb = (unsigned short*)d_ws;
        const int preBlocks = (nEnt + 8 * 4 - 1) / (8 * 4);   // 8 rows/wave
        we_kernel<<<preBlocks, 256, 0, stream>>>(entity_emb, W, WEb, nEnt);
        const int mainBlocks = (nPairs + 3) / 4;              // 1 wave/pair
        kgcn_main<<<mainBlocks, 256, 0, stream>>>(pairs, adj_entity, adj_relation,
                                                  WEb, relation_emb, user_emb,
                                                  W, b, out, nPairs);
    } else {
        const int nBlocks = (nPairs + 1) / 2;
        kgcn_fallback<<<nBlocks, 256, 0, stream>>>(pairs, adj_entity, adj_relation,
                                                   entity_emb, relation_emb, user_emb,
                                                   W, b, out, nPairs);
    }
}